// Round 7
// baseline (321.366 us; speedup 1.0000x reference)
//
#include <hip/hip_runtime.h>
#include <hip/hip_bf16.h>

typedef __attribute__((ext_vector_type(8))) short bf16x8;
typedef __attribute__((ext_vector_type(4))) short bf16x4;
typedef __attribute__((ext_vector_type(4))) float f32x4;

__device__ __forceinline__ unsigned short f2bf(float f) {
  union { float f; unsigned int u; } v; v.f = f;
  unsigned int r = (v.u + 0x7fffu + ((v.u >> 16) & 1u)) >> 16;
  return (unsigned short)r;
}

__device__ __forceinline__ unsigned int pk2bf(float a, float b) {
  float2 t; t.x = a; t.y = b;
  __hip_bfloat162 h = __float22bfloat162_rn(t);
  union { __hip_bfloat162 h; unsigned int u; } cv; cv.h = h;
  return cv.u;
}

__device__ __forceinline__ void g2l16(unsigned short* lds, const unsigned short* g) {
  __builtin_amdgcn_global_load_lds(
      (const __attribute__((address_space(1))) unsigned int*)g,
      (__attribute__((address_space(3))) unsigned int*)lds, 16, 0, 0);
}

// ---------------- prep kernels ----------------

__global__ __launch_bounds__(256) void cast_hs_kernel(const float* __restrict__ in,
                                                      unsigned short* __restrict__ out) {
  size_t i = (size_t)blockIdx.x * 256 + threadIdx.x;
  float4 v = ((const float4*)in)[i];
  ushort4 o;
  o.x = f2bf(v.x); o.y = f2bf(v.y); o.z = f2bf(v.z); o.w = f2bf(v.w);
  ((ushort4*)out)[i] = o;
}

// One launch transposes all four weight matrices. z selects matrix.
// src [2048][N] fp32 -> dst [N][2048] bf16.
__global__ __launch_bounds__(256) void transpose_all_kernel(
    const float* __restrict__ Wq, const float* __restrict__ Wk,
    const float* __restrict__ Wv, const float* __restrict__ Wo,
    unsigned short* __restrict__ Wqkv, unsigned short* __restrict__ WoT) {
  __shared__ float tile[32][33];
  int z = blockIdx.z;
  const float* src; unsigned short* dst; int N;
  if (z == 0)      { src = Wq; dst = Wqkv;                          N = 2048; }
  else if (z == 1) { src = Wk; dst = Wqkv + (size_t)2048 * 2048;    N = 512; }
  else if (z == 2) { src = Wv; dst = Wqkv + (size_t)2560 * 2048;    N = 512; }
  else             { src = Wo; dst = WoT;                           N = 2048; }
  if (blockIdx.x * 32 >= N) return;
  int n0 = blockIdx.x * 32, k0 = blockIdx.y * 32;
  int t = threadIdx.x;
  for (int i = 0; i < 4; ++i) {
    int linear = i * 256 + t;
    int kr = linear >> 5, nc = linear & 31;
    tile[kr][nc] = src[(size_t)(k0 + kr) * N + (n0 + nc)];
  }
  __syncthreads();
  for (int i = 0; i < 4; ++i) {
    int linear = i * 256 + t;
    int nr = linear >> 5, kc = linear & 31;
    dst[(size_t)(n0 + nr) * 2048 + (k0 + kc)] = f2bf(tile[kc][nr]);
  }
}

// ---------------- fused QKV GEMM: 256x256 tile, 8-phase pipeline ----------------
// The m201 regime (256^2 + 8-phase + swizzle + setprio): 8 waves (2M x 4N),
// per-wave output 128x64, BK=64, LDS 128 KB (2 dbuf x 2 half x [128][64] x A,B).
// Iteration computes K-steps 2i (buf0, ph1-4) and 2i+1 (buf1, ph5-8).
// Staging: ph1 = A-halves of 2i+1, ph2 = B-halves (buf1 is free from prev
// ph8's barrier); ph5/ph6 = A/B halves of 2i+2 into buf0 (free after ph4).
// Gates: vmcnt(0) at ph4 and ph8 only -- drains loads issued 2-3 phases
// (~1500 cyc) earlier, so normally free; loads span ~3 barriers.
// Swizzle: pre-swizzled GLOBAL source column (ch^(row&7)), linear LDS dest
// (rule #21), same XOR on ds_read -> conflict-free b128 at 128B stride
// (correctness-verified in R2/R6).
// Tail (i=15) stages K-steps 32/33: OOB-safe reads into adjacent workspace
// buffers, never consumed.

#define QSCALE 0.18033688011112042f  // 0.125 * log2(e)

#define QKV_PHASE(BUFO, MH, KK, SSTAGE, STA, DOSTAGE, GATE)                          \
  do {                                                                               \
    __builtin_amdgcn_sched_barrier(0);                                               \
    bf16x8 af[4], bfr[4];                                                            \
    _Pragma("unroll")                                                                \
    for (int m4 = 0; m4 < 4; ++m4) {                                                 \
      int lr = ((MH) * 4 + m4) * 16 + l16;                                           \
      af[m4] = *(const bf16x8*)(sA + (BUFO) + wm * 8192 + lr * 64 +                  \
                                ((((KK) * 4 + quad) ^ (lr & 7)) * 8));               \
    }                                                                                \
    _Pragma("unroll")                                                                \
    for (int nr = 0; nr < 4; ++nr) {                                                 \
      int cb = wn * 64 + nr * 16;                                                    \
      int lc = (cb & 127) + l16;                                                     \
      bfr[nr] = *(const bf16x8*)(sB + (BUFO) + (cb >> 7) * 8192 + lc * 64 +          \
                                 ((((KK) * 4 + quad) ^ (lc & 7)) * 8));              \
    }                                                                                \
    if (DOSTAGE) {                                                                   \
      const unsigned short* src_ = (STA) ? A : Bt;                                   \
      unsigned short* dst_ = (STA) ? sA : sB;                                        \
      int b0_ = (STA) ? bm0 : bn0;                                                   \
      int dbase_ = ((SSTAGE) & 1) * 16384;                                           \
      _Pragma("unroll")                                                              \
      for (int h_ = 0; h_ < 2; ++h_)                                                 \
        _Pragma("unroll")                                                            \
        for (int ii_ = 0; ii_ < 2; ++ii_) {                                          \
          int lin_ = ii_ * 512 + t;                                                  \
          int row_ = lin_ >> 3, ch_ = lin_ & 7;                                      \
          g2l16(dst_ + dbase_ + h_ * 8192 + lin_ * 8,                                \
                src_ + (size_t)(b0_ + h_ * 128 + row_) * 2048 + (SSTAGE) * 64 +      \
                    ((ch_ ^ (row_ & 7)) * 8));                                       \
        }                                                                            \
    }                                                                                \
    if (GATE) asm volatile("s_waitcnt vmcnt(0)" ::: "memory");                       \
    __builtin_amdgcn_s_barrier();                                                    \
    asm volatile("s_waitcnt lgkmcnt(0)" ::: "memory");                               \
    __builtin_amdgcn_sched_barrier(0);                                               \
    __builtin_amdgcn_s_setprio(1);                                                   \
    _Pragma("unroll")                                                                \
    for (int m4 = 0; m4 < 4; ++m4)                                                   \
      _Pragma("unroll")                                                              \
      for (int nr = 0; nr < 4; ++nr)                                                 \
        acc[(MH) * 4 + m4][nr] = __builtin_amdgcn_mfma_f32_16x16x32_bf16(            \
            af[m4], bfr[nr], acc[(MH) * 4 + m4][nr], 0, 0, 0);                       \
    __builtin_amdgcn_s_setprio(0);                                                   \
  } while (0)

__global__ __launch_bounds__(512, 2) void gemm_qkv_kernel(
    const unsigned short* __restrict__ A, const unsigned short* __restrict__ Bt,
    const float* __restrict__ bq, const float* __restrict__ bk, const float* __restrict__ bv,
    unsigned short* __restrict__ Qb, unsigned short* __restrict__ Kb,
    unsigned short* __restrict__ Vtb) {
  __shared__ __align__(16) unsigned short lds[65536];   // 128 KB
  unsigned short* sA = lds;            // [2 buf][2 half][128][64]
  unsigned short* sB = lds + 32768;
  int bm0 = blockIdx.y * 256, bn0 = blockIdx.x * 256;
  int t = threadIdx.x;
  int lane = t & 63, l16 = lane & 15, quad = lane >> 4;
  int w = t >> 6, wm = w >> 2, wn = w & 3;

  f32x4 zero = {0.f, 0.f, 0.f, 0.f};
  f32x4 acc[8][4];
#pragma unroll
  for (int m = 0; m < 8; ++m)
#pragma unroll
    for (int n = 0; n < 4; ++n) acc[m][n] = zero;

  // prologue: stage K-step 0 (all 4 halves of A and B) into buf0
#pragma unroll
  for (int h = 0; h < 2; ++h)
#pragma unroll
    for (int ii = 0; ii < 2; ++ii) {
      int lin = ii * 512 + t;
      int row = lin >> 3, ch = lin & 7;
      int kofs = (ch ^ (row & 7)) * 8;
      g2l16(sA + h * 8192 + lin * 8, A + (size_t)(bm0 + h * 128 + row) * 2048 + kofs);
      g2l16(sB + h * 8192 + lin * 8, Bt + (size_t)(bn0 + h * 128 + row) * 2048 + kofs);
    }
  asm volatile("s_waitcnt vmcnt(0)" ::: "memory");
  __builtin_amdgcn_s_barrier();

  for (int i = 0; i < 16; ++i) {
    int s1 = 2 * i + 1, s2 = 2 * i + 2;
    QKV_PHASE(0,     0, 0, s1, 1, 1, 0);   // ph1: stage A halves of s1 -> buf1
    QKV_PHASE(0,     0, 1, s1, 0, 1, 0);   // ph2: stage B halves of s1 -> buf1
    QKV_PHASE(0,     1, 0, 0,  0, 0, 0);   // ph3
    QKV_PHASE(0,     1, 1, 0,  0, 0, 1);   // ph4: vmcnt(0) -> buf1 ready
    QKV_PHASE(16384, 0, 0, s2, 1, 1, 0);   // ph5: stage A halves of s2 -> buf0
    QKV_PHASE(16384, 0, 1, s2, 0, 1, 0);   // ph6: stage B halves of s2 -> buf0
    QKV_PHASE(16384, 1, 0, 0,  0, 0, 0);   // ph7
    QKV_PHASE(16384, 1, 1, 0,  0, 0, 1);   // ph8: vmcnt(0) -> buf0 ready
  }
  asm volatile("s_waitcnt vmcnt(0) lgkmcnt(0)" ::: "memory");
  __syncthreads();

  // ---- epilogue: per-128x128 quadrant, verified R0 repack/store code ----
  unsigned short* smem = lds;
  const int SP = 136;
  bool isV = (bn0 >= 2560);
  bool isQ = (bn0 < 2048);
  const float* bias = isQ ? bq : (bn0 < 2560 ? bk : bv);
  int nbase = isQ ? 0 : (bn0 < 2560 ? 2048 : 2560);

  for (int qm = 0; qm < 2; ++qm) {
    for (int qn = 0; qn < 2; ++qn) {
      int bm0q = bm0 + qm * 128, bn0q = bn0 + qn * 128;
      if (wm == qm && (wn >> 1) == qn) {
#pragma unroll
        for (int nrep = 0; nrep < 4; ++nrep) {
          int nl = (wn & 1) * 64 + nrep * 16 + l16;
          float bb = bias[bn0q + nl - nbase];
#pragma unroll
          for (int mrep = 0; mrep < 8; ++mrep)
#pragma unroll
            for (int r = 0; r < 4; ++r) {
              int ml = mrep * 16 + quad * 4 + r;
              float fv = acc[mrep][nrep][r] + bb;
              if (isQ) fv *= QSCALE;
              unsigned short val = f2bf(fv);
              if (isV) smem[nl * SP + ml] = val;
              else     smem[ml * SP + nl] = val;
            }
        }
      }
      __syncthreads();
      int b = bm0q >> 11, s0 = bm0q & 2047;
      if (isQ) {                 // Q -> [b][h][s][64]
        for (int i2 = 0; i2 < 4; ++i2) {
          int idx = i2 * 512 + t;
          int sub = idx >> 10, s_l = (idx >> 3) & 127, dch = (idx & 7) * 8;
          bf16x8 v = *(const bf16x8*)(smem + s_l * SP + sub * 64 + dch);
          int n = bn0q + sub * 64 + dch;
          int h = n >> 6, d = n & 63;
          *(bf16x8*)(Qb + (((size_t)b * 32 + h) * 2048 + s0 + s_l) * 64 + d) = v;
        }
      } else if (!isV) {         // K -> [b][g][s][64]
        for (int i2 = 0; i2 < 4; ++i2) {
          int idx = i2 * 512 + t;
          int sub = idx >> 10, s_l = (idx >> 3) & 127, dch = (idx & 7) * 8;
          bf16x8 v = *(const bf16x8*)(smem + s_l * SP + sub * 64 + dch);
          int nn = bn0q + sub * 64 + dch - 2048;
          int g = nn >> 6, d = nn & 63;
          *(bf16x8*)(Kb + (((size_t)b * 8 + g) * 2048 + s0 + s_l) * 64 + d) = v;
        }
      } else {                   // V -> [b][g][d][s] (transposed)
        for (int i2 = 0; i2 < 4; ++i2) {
          int idx = i2 * 512 + t;
          int nl = idx >> 4, sj = (idx & 15) * 8;
          bf16x8 v = *(const bf16x8*)(smem + nl * SP + sj);
          int nn = bn0q + nl - 2560;
          int g = nn >> 6, d = nn & 63;
          *(bf16x8*)(Vtb + (((size_t)b * 8 + g) * 64 + d) * 2048 + s0 + sj) = v;
        }
      }
      __syncthreads();
    }
  }
}

// ---------------- flash attention (R5, unchanged -- 93 us verified) ----------------
// grid: (S/256, NUM_HEAD, B) = 512 blocks (2/CU), block 512 (8 waves).
// Each wave owns TWO 16-row q-tiles; 2-phase double-buffered staging.
// S^T = K @ Q^T (swapped 16x16x32) -> P stays in registers; l via ones-MFMA.
// Q pre-scaled by 0.125*log2(e); p = exp2(K.Q - 10) (exact softmax shift).

__global__ __launch_bounds__(512, 4) void attn_kernel(
    const unsigned short* __restrict__ Qb, const unsigned short* __restrict__ Kb,
    const unsigned short* __restrict__ Vtb, unsigned short* __restrict__ AttnB) {
  __shared__ __align__(16) unsigned short Kt[2 * 4096];   // [buf][dchunk][key][8]
  __shared__ __align__(16) unsigned short Vt[2 * 4096];   // [buf][keychunk][d][8]
  int qt = blockIdx.x, h = blockIdx.y, b = blockIdx.z;
  int g = h >> 2;
  int t = threadIdx.x, w = t >> 6, lane = t & 63, l16 = lane & 15, quad = lane >> 4;

  const unsigned short* qb0 =
      Qb + (((size_t)b * 32 + h) * 2048 + qt * 256 + w * 16 + l16) * 64 + quad * 8;
  const unsigned short* qb1 = qb0 + (size_t)128 * 64;
  bf16x8 aQ0a = *(const bf16x8*)(qb0);
  bf16x8 aQ1a = *(const bf16x8*)(qb0 + 32);
  bf16x8 aQ0b = *(const bf16x8*)(qb1);
  bf16x8 aQ1b = *(const bf16x8*)(qb1 + 32);

  const unsigned short* kbase = Kb + ((size_t)b * 8 + g) * (2048 * 64);
  const unsigned short* vbase = Vtb + ((size_t)b * 8 + g) * (64 * 2048);
  int r_ = t & 63, c_ = t >> 6;
  const unsigned short* gK = kbase + (size_t)r_ * 64 + c_ * 8;    // + kb*4096
  const unsigned short* gV = vbase + (size_t)r_ * 2048 + c_ * 8;  // + kb*64

  auto stage = [&](int buf, int kb) {
    g2l16(Kt + buf * 4096 + t * 8, gK + (size_t)kb * 4096);
    g2l16(Vt + buf * 4096 + t * 8, gV + (size_t)kb * 64);
  };

  f32x4 zero = {0.f, 0.f, 0.f, 0.f};
  f32x4 m10 = {-10.f, -10.f, -10.f, -10.f};
  union { unsigned short s[4]; bf16x4 v; } ones;
  ones.s[0] = 0x3F80; ones.s[1] = 0x3F80; ones.s[2] = 0x3F80; ones.s[3] = 0x3F80;

  f32x4 oA[4], oB[4], olA, olB;
  for (int dt = 0; dt < 4; ++dt) { oA[dt] = zero; oB[dt] = zero; }
  olA = zero; olB = zero;

  stage(0, 0);
  __syncthreads();                       // buf0 ready
  int cur = 0;
  for (int kb = 0; kb < 32; ++kb) {
    if (kb < 31) stage(cur ^ 1, kb + 1);   // issue next K/V tile early
    const unsigned short* Kc = Kt + cur * 4096;
    const unsigned short* Vc = Vt + cur * 4096;

    for (int nt = 0; nt < 4; ++nt) {
      bf16x8 bk0 = *(const bf16x8*)(Kc + (quad * 64 + nt * 16 + l16) * 8);
      bf16x8 bk1 = *(const bf16x8*)(Kc + ((quad + 4) * 64 + nt * 16 + l16) * 8);
      f32x4 stA = __builtin_amdgcn_mfma_f32_16x16x32_bf16(bk0, aQ0a, m10, 0, 0, 0);
      stA = __builtin_amdgcn_mfma_f32_16x16x32_bf16(bk1, aQ1a, stA, 0, 0, 0);
      f32x4 stB = __builtin_amdgcn_mfma_f32_16x16x32_bf16(bk0, aQ0b, m10, 0, 0, 0);
      stB = __builtin_amdgcn_mfma_f32_16x16x32_bf16(bk1, aQ1b, stB, 0, 0, 0);

      union { unsigned int u[2]; bf16x4 v; } paA, paB;
      paA.u[0] = pk2bf(__builtin_amdgcn_exp2f(stA[0]), __builtin_amdgcn_exp2f(stA[1]));
      paA.u[1] = pk2bf(__builtin_amdgcn_exp2f(stA[2]), __builtin_amdgcn_exp2f(stA[3]));
      paB.u[0] = pk2bf(__builtin_amdgcn_exp2f(stB[0]), __builtin_amdgcn_exp2f(stB[1]));
      paB.u[1] = pk2bf(__builtin_amdgcn_exp2f(stB[2]), __builtin_amdgcn_exp2f(stB[3]));

      olA = __builtin_amdgcn_mfma_f32_16x16x16bf16_1k(paA.v, ones.v, olA, 0, 0, 0);
      olB = __builtin_amdgcn_mfma_f32_16x16x16bf16_1k(paB.v, ones.v, olB, 0, 0, 0);

      int c = nt * 2 + (quad >> 1);
      int ho = (quad & 1) * 4;
      for (int dt = 0; dt < 4; ++dt) {
        bf16x4 bv = *(const bf16x4*)(Vc + (c * 64 + dt * 16 + l16) * 8 + ho);
        oA[dt] = __builtin_amdgcn_mfma_f32_16x16x16bf16_1k(paA.v, bv, oA[dt], 0, 0, 0);
        oB[dt] = __builtin_amdgcn_mfma_f32_16x16x16bf16_1k(paB.v, bv, oB[dt], 0, 0, 0);
      }
    }
    __syncthreads();   // reads of cur done + next tile landed
    cur ^= 1;
  }

  for (int r = 0; r < 4; ++r) {
    float invA = 1.f / olA[r];
    float invB = 1.f / olB[r];
    int srow0 = qt * 256 + w * 16 + quad * 4 + r;
    size_t base0 = ((size_t)b * 2048 + srow0) * 2048 + h * 64;
    size_t base1 = base0 + (size_t)128 * 2048;
    for (int dt = 0; dt < 4; ++dt) {
      AttnB[base0 + dt * 16 + l16] = f2bf(oA[dt][r] * invA);
      AttnB[base1 + dt * 16 + l16] = f2bf(oB[dt][r] * invB);
    }
  }
}

// ---------------- output GEMM (R0 body, BK=32 -- measured-best at 128^2) ----------------
// A: AttnB [4096][2048] bf16, Bt: WoT [2048][2048] bf16, out fp32 + bias

__global__ __launch_bounds__(256) void gemm_out_kernel(
    const unsigned short* __restrict__ A, const unsigned short* __restrict__ Bt,
    const float* __restrict__ bo, float* __restrict__ out) {
  __shared__ __align__(16) unsigned short sA[128 * 32];
  __shared__ __align__(16) unsigned short sB[128 * 32];
  const int K = 2048;
  int bm0 = blockIdx.y * 128, bn0 = blockIdx.x * 128;
  int t = threadIdx.x;
  int w = t >> 6, lane = t & 63, l16 = lane & 15, quad = lane >> 4;
  int wm = (w & 1) * 64, wn = (w >> 1) * 64;
  f32x4 zero = {0.f, 0.f, 0.f, 0.f};
  f32x4 acc[4][4];
  for (int mt = 0; mt < 4; ++mt)
    for (int nt = 0; nt < 4; ++nt) acc[mt][nt] = zero;

  for (int k0 = 0; k0 < K; k0 += 32) {
    for (int i = 0; i < 2; ++i) {
      int linear = i * 256 + t;
      int row = linear >> 2, kofs = (linear & 3) * 8;
      g2l16(sA + linear * 8, A + (size_t)(bm0 + row) * K + k0 + kofs);
      g2l16(sB + linear * 8, Bt + (size_t)(bn0 + row) * K + k0 + kofs);
    }
    __syncthreads();
    bf16x8 af[4], bfr[4];
    for (int mt = 0; mt < 4; ++mt)
      af[mt] = *(const bf16x8*)(sA + (wm + mt * 16 + l16) * 32 + quad * 8);
    for (int nt = 0; nt < 4; ++nt)
      bfr[nt] = *(const bf16x8*)(sB + (wn + nt * 16 + l16) * 32 + quad * 8);
    for (int mt = 0; mt < 4; ++mt)
      for (int nt = 0; nt < 4; ++nt)
        acc[mt][nt] = __builtin_amdgcn_mfma_f32_16x16x32_bf16(af[mt], bfr[nt], acc[mt][nt], 0, 0, 0);
    __syncthreads();
  }

  for (int nt = 0; nt < 4; ++nt) {
    int n = bn0 + wn + nt * 16 + l16;
    float bias = bo[n];
    for (int mt = 0; mt < 4; ++mt)
      for (int r = 0; r < 4; ++r) {
        int m = bm0 + wm + mt * 16 + quad * 4 + r;
        out[(size_t)m * 2048 + n] = acc[mt][nt][r] + bias;
      }
  }
}

// ---------------- launch ----------------

extern "C" void kernel_launch(void* const* d_in, const int* in_sizes, int n_in,
                              void* d_out, int out_size, void* d_ws, size_t ws_size,
                              hipStream_t stream) {
  const float* hs = (const float*)d_in[0];
  const float* Wq = (const float*)d_in[1];
  const float* bq = (const float*)d_in[2];
  const float* Wk = (const float*)d_in[3];
  const float* bk = (const float*)d_in[4];
  const float* Wv = (const float*)d_in[5];
  const float* bv = (const float*)d_in[6];
  const float* Wo = (const float*)d_in[7];
  const float* bo = (const float*)d_in[8];
  float* out = (float*)d_out;

  char* ws = (char*)d_ws;
  unsigned short* hsb   = (unsigned short*)(ws);                 // 16 MB  [4096][2048]
  unsigned short* Wqkv  = (unsigned short*)(ws + 16777216);      // 12 MB  [3072][2048]
  unsigned short* WoT   = (unsigned short*)(ws + 29360128);      // 8 MB   [2048][2048]
  unsigned short* Qb    = (unsigned short*)(ws + 37748736);      // 16 MB  [2][32][2048][64]
  unsigned short* Kb    = (unsigned short*)(ws + 54525952);      // 4 MB   [2][8][2048][64]
  unsigned short* Vtb   = (unsigned short*)(ws + 58720256);      // 4 MB   [2][8][64][2048]
  unsigned short* AttnB = (unsigned short*)(ws + 62914560);      // 16 MB  [4096][2048]

  hipLaunchKernelGGL(cast_hs_kernel, dim3(8192), dim3(256), 0, stream, hs, hsb);
  hipLaunchKernelGGL(transpose_all_kernel, dim3(64, 64, 4), dim3(256), 0, stream,
                     Wq, Wk, Wv, Wo, Wqkv, WoT);
  hipLaunchKernelGGL(gemm_qkv_kernel, dim3(12, 16), dim3(512), 0, stream,
                     hsb, Wqkv, bq, bk, bv, Qb, Kb, Vtb);
  hipLaunchKernelGGL(attn_kernel, dim3(8, 32, 2), dim3(512), 0, stream, Qb, Kb, Vtb, AttnB);
  hipLaunchKernelGGL(gemm_out_kernel, dim3(16, 32), dim3(256), 0, stream, AttnB, WoT, bo, out);
}